// Round 4
// baseline (234.461 us; speedup 1.0000x reference)
//
#include <hip/hip_runtime.h>
#include <math.h>

// Conv-KNRM on MI355X. B=128, QLEN=30, DLEN=256, EMB=300 (pad 320), C=128.
//
// Pipeline:
//   prep_w : w fp32 [C,E,k] -> wt bf16 [plane(g,j)][c][320] (e zero-pad)
//   conv2  : fused 3-gram conv. Block = 64 l-rows x 384 cols (3 grams x 128c).
//            A (x rows) staged once to LDS (bf16, stride 328 = 2-way-free);
//            B frags read DIRECTLY from global (L2-resident weights);
//            NO barriers in K-loop. bias+relu+L2norm epilogue -> bf16 [g][b][l][c]
//   pool_mfma : LDS-free MFMA cos, RBF x11, d-sum -> pkq4 partials
//   final_kernel : sum chunks, log/clip/qmask/sum_q dot dense_w -> out[128]
//
// ws: wt bf16 245760 | qn bf16 1474560 | dn bf16 12582912 | pkq4 f32 1520640

typedef __bf16 bf16x8 __attribute__((ext_vector_type(8)));
typedef float f32x4 __attribute__((ext_vector_type(4)));

#if __has_builtin(__builtin_amdgcn_exp2f)
#define EXP2F(x) __builtin_amdgcn_exp2f(x)
#else
#define EXP2F(x) exp2f(x)
#endif

static __device__ __forceinline__ unsigned short f2bf(float f) {
  union { float f; unsigned int u; } v; v.f = f;
  unsigned int r = v.u + 0x7FFFu + ((v.u >> 16) & 1u);  // RNE
  return (unsigned short)(r >> 16);
}

__global__ __launch_bounds__(256) void prep_w(
    const float* __restrict__ w1, const float* __restrict__ w2,
    const float* __restrict__ w3, unsigned short* __restrict__ wt) {
  int idx = blockIdx.x * 256 + threadIdx.x;
  if (idx >= 245760) return;  // 6 planes * 128 c * 320 e
  int e = idx % 320;
  int c = (idx / 320) & 127;
  int p = idx / 40960;
  const float* w; int k, j;
  if (p == 0)      { w = w1; k = 1; j = 0; }
  else if (p <= 2) { w = w2; k = 2; j = p - 1; }
  else             { w = w3; k = 3; j = p - 3; }
  float v = (e < 300) ? w[(c * 300 + e) * k + j] : 0.0f;
  wt[idx] = f2bf(v);
}

// Fused conv. Block: 256 thr = 4 waves; output 64 rows x 384 cols.
// Col-block cb = ni*4 + w (24 blocks of 16): gram g = ni>>1 (compile-time!),
// channel ch = ((ni&1)*4 + w)*16 + lrow. Wave tile: MI*16 rows x 96 cols.
// K-loop: ec (10 x 32e) x j (taps): af[MI] from LDS, bf from GLOBAL, MFMA.
template<int MI>
__global__ __launch_bounds__(256, 3) void conv2(
    const float* __restrict__ x, int L,
    const unsigned short* __restrict__ wt,
    const float* __restrict__ b1, const float* __restrict__ b2,
    const float* __restrict__ b3,
    unsigned short* __restrict__ out) {
  constexpr int ROWS = MI * 16 + 2;
  const int b  = blockIdx.y;
  const int l0 = blockIdx.x * 64;

  __shared__ unsigned short As[ROWS][328];  // stride 328: b128 reads 2-way
  __shared__ float ssq[3][64];

  const int t = threadIdx.x;
  const int w = __builtin_amdgcn_readfirstlane(t >> 6);
  const int lane = t & 63;
  const int quad = lane >> 4, lrow = lane & 15;

  if (t < 192) ssq[t >> 6][t & 63] = 0.0f;

  // stage A once: fp32 -> bf16, rows l0..l0+ROWS-1, cols 0..319 (zero pad)
  const float* xb = x + (size_t)b * L * 300;
  for (int idx = t; idx < ROWS * 80; idx += 256) {
    int r = idx / 80, e4 = idx % 80;
    int e = e4 * 4;
    int l = l0 + r;
    float4 v = make_float4(0.f, 0.f, 0.f, 0.f);
    if (l < L && e < 300) v = *reinterpret_cast<const float4*>(xb + l * 300 + e);
    unsigned int lo = (unsigned int)f2bf(v.x) | ((unsigned int)f2bf(v.y) << 16);
    unsigned int hi = (unsigned int)f2bf(v.z) | ((unsigned int)f2bf(v.w) << 16);
    *reinterpret_cast<uint2*>(&As[r][e]) = make_uint2(lo, hi);
  }
  __syncthreads();

  const float* biases[3] = {b1, b2, b3};
  const int pstart[3] = {0, 1, 3};
  float bv[6];
  #pragma unroll
  for (int ni = 0; ni < 6; ++ni)
    bv[ni] = biases[ni >> 1][((ni & 1) * 4 + w) * 16 + lrow];

  f32x4 acc[MI][6];
  #pragma unroll
  for (int mi = 0; mi < MI; ++mi)
    #pragma unroll
    for (int ni = 0; ni < 6; ++ni) acc[mi][ni] = (f32x4){0.f, 0.f, 0.f, 0.f};

  // K-loop: NO barriers. af from LDS, bf from global (L2-resident weights).
  #pragma unroll 2
  for (int ec = 0; ec < 10; ++ec) {
    #pragma unroll
    for (int j = 0; j < 3; ++j) {
      bf16x8 af[MI];
      #pragma unroll
      for (int mi = 0; mi < MI; ++mi)
        af[mi] = *reinterpret_cast<const bf16x8*>(
            &As[mi * 16 + lrow + j][ec * 32 + quad * 8]);
      #pragma unroll
      for (int ni = 0; ni < 6; ++ni) {
        constexpr int dummy = 0; (void)dummy;
        const int g = ni >> 1;
        if (j <= g) {
          const int ch = ((ni & 1) * 4 + w) * 16 + lrow;
          bf16x8 bf = *reinterpret_cast<const bf16x8*>(
              wt + (size_t)(pstart[g] + j) * 40960 + ch * 320 + ec * 32 + quad * 8);
          #pragma unroll
          for (int mi = 0; mi < MI; ++mi)
            acc[mi][ni] = __builtin_amdgcn_mfma_f32_16x16x32_bf16(
                af[mi], bf, acc[mi][ni], 0, 0, 0);
        }
      }
    }
  }

  // epilogue: ssq per (gram, row) across waves, then normalize + store
  #pragma unroll
  for (int mi = 0; mi < MI; ++mi) {
    #pragma unroll
    for (int r = 0; r < 4; ++r) {
      #pragma unroll
      for (int g = 0; g < 3; ++g) {
        float y0 = fmaxf(acc[mi][2 * g + 0][r] + bv[2 * g + 0], 0.f);
        float y1 = fmaxf(acc[mi][2 * g + 1][r] + bv[2 * g + 1], 0.f);
        float p = y0 * y0 + y1 * y1;
        p += __shfl_xor(p, 1); p += __shfl_xor(p, 2);
        p += __shfl_xor(p, 4); p += __shfl_xor(p, 8);
        if (lrow == 0) atomicAdd(&ssq[g][mi * 16 + quad * 4 + r], p);
      }
    }
  }
  __syncthreads();

  #pragma unroll
  for (int mi = 0; mi < MI; ++mi) {
    #pragma unroll
    for (int r = 0; r < 4; ++r) {
      int row = mi * 16 + quad * 4 + r;
      int l = l0 + row;
      if (l < L) {
        #pragma unroll
        for (int g = 0; g < 3; ++g) {
          float inv = 1.0f / (sqrtf(ssq[g][row]) + 1e-13f);
          #pragma unroll
          for (int h = 0; h < 2; ++h) {
            int ni = 2 * g + h;
            int ch = ((ni & 1) * 4 + w) * 16 + lrow;
            float y = fmaxf(acc[mi][ni][r] + bv[ni], 0.f);
            out[((size_t)(g * 128 + b) * L + l) * 128 + ch] = f2bf(y * inv);
          }
        }
      }
    }
  }
}

// One wave per (tg, b, dchunk of 64). A = doc rows (M=d), B = query rows
// (N=q), K = c = 128. RBF features accumulate per-lane; quad shfl reduce.
__global__ __launch_bounds__(64) void pool_mfma(
    const unsigned short* __restrict__ qn, const unsigned short* __restrict__ dn,
    const float* __restrict__ qmask, const float* __restrict__ dmask,
    float* __restrict__ pkq4) {
  const float MU[11] = {1.0f, 0.9f, 0.7f, 0.5f, 0.3f, 0.1f,
                        -0.1f, -0.3f, -0.5f, -0.7f, -0.9f};
  const float NEGC[11] = {-721347.52f, -72.134752f, -72.134752f, -72.134752f,
                          -72.134752f, -72.134752f, -72.134752f, -72.134752f,
                          -72.134752f, -72.134752f, -72.134752f};
  const int tg    = blockIdx.x >> 2;
  const int chunk = blockIdx.x & 3;
  const int b     = blockIdx.y;
  const int lane  = threadIdx.x;
  const int quad  = lane >> 4, l15 = lane & 15;
  const int d0    = chunk * 64;

  const unsigned short* dslab = dn + (size_t)(tg * 128 + b) * 256 * 128;

  bf16x8 aD[4][4];
  #pragma unroll
  for (int mi = 0; mi < 4; ++mi)
    #pragma unroll
    for (int kt = 0; kt < 4; ++kt)
      aD[mi][kt] = *reinterpret_cast<const bf16x8*>(
          dslab + (size_t)(d0 + mi * 16 + l15) * 128 + kt * 32 + quad * 8);

  float dmv[4][4];
  #pragma unroll
  for (int mi = 0; mi < 4; ++mi)
    #pragma unroll
    for (int r = 0; r < 4; ++r)
      dmv[mi][r] = dmask[b * 256 + d0 + mi * 16 + quad * 4 + r];

  float qmv[2];
  qmv[0] = qmask[b * 30 + l15];
  qmv[1] = (16 + l15 < 30) ? qmask[b * 30 + 16 + l15] : 0.0f;

  #pragma unroll 1
  for (int ig = 0; ig < 3; ++ig) {
    const unsigned short* qslab = qn + (size_t)(ig * 128 + b) * 30 * 128;

    bf16x8 bQ[2][4];
    #pragma unroll
    for (int ni = 0; ni < 2; ++ni)
      #pragma unroll
      for (int kt = 0; kt < 4; ++kt)
        bQ[ni][kt] = *reinterpret_cast<const bf16x8*>(
            qslab + (size_t)(ni * 16 + l15) * 128 + kt * 32 + quad * 8);

    f32x4 acc[4][2];
    #pragma unroll
    for (int mi = 0; mi < 4; ++mi)
      #pragma unroll
      for (int ni = 0; ni < 2; ++ni) acc[mi][ni] = (f32x4){0.f, 0.f, 0.f, 0.f};

    #pragma unroll
    for (int kt = 0; kt < 4; ++kt)
      #pragma unroll
      for (int mi = 0; mi < 4; ++mi)
        #pragma unroll
        for (int ni = 0; ni < 2; ++ni)
          acc[mi][ni] = __builtin_amdgcn_mfma_f32_16x16x32_bf16(
              aD[mi][kt], bQ[ni][kt], acc[mi][ni], 0, 0, 0);

    float feat[2][11];
    #pragma unroll
    for (int ni = 0; ni < 2; ++ni)
      #pragma unroll
      for (int kk = 0; kk < 11; ++kk) feat[ni][kk] = 0.0f;

    #pragma unroll
    for (int mi = 0; mi < 4; ++mi) {
      #pragma unroll
      for (int r = 0; r < 4; ++r) {
        #pragma unroll
        for (int ni = 0; ni < 2; ++ni) {
          float m  = qmv[ni] * dmv[mi][r];
          float cm = acc[mi][ni][r] * m;
          #pragma unroll
          for (int kk = 0; kk < 11; ++kk) {
            float d2 = cm - MU[kk];
            feat[ni][kk] += EXP2F(d2 * d2 * NEGC[kk]) * m;
          }
        }
      }
    }

    #pragma unroll
    for (int ni = 0; ni < 2; ++ni)
      #pragma unroll
      for (int kk = 0; kk < 11; ++kk) {
        float v = feat[ni][kk];
        v += __shfl_xor(v, 16);
        v += __shfl_xor(v, 32);
        feat[ni][kk] = v;
      }

    if (quad == 0) {
      const int pair = ig * 3 + tg;
      #pragma unroll
      for (int ni = 0; ni < 2; ++ni) {
        int q = ni * 16 + l15;
        if (q < 30) {
          float* p = pkq4 +
              (((size_t)(chunk * 9 + pair) * 128 + b) * 30 + q) * 11;
          #pragma unroll
          for (int kk = 0; kk < 11; ++kk) p[kk] = feat[ni][kk];
        }
      }
    }
  }
}

__global__ __launch_bounds__(128) void final_kernel(
    const float* __restrict__ pkq4, const float* __restrict__ qmask,
    const float* __restrict__ dw, float* __restrict__ out) {
  const int CH = 9 * 128 * 30 * 11;  // 380160
  const int b = blockIdx.x;
  const int t = threadIdx.x;
  float s = 0.0f;
  for (int idx = t; idx < 9 * 30 * 11; idx += 128) {
    int pair = idx / 330;
    int rem  = idx % 330;
    int q    = rem / 11;
    int kk   = rem % 11;
    size_t base = (((size_t)pair * 128 + b) * 30 + q) * 11 + kk;
    float v = pkq4[base] + pkq4[base + CH] + pkq4[base + 2 * CH] +
              pkq4[base + 3 * CH];
    s += __logf(fmaxf(v, 1e-10f)) * 0.01f * qmask[b * 30 + q] * dw[pair * 11 + kk];
  }
  s += __shfl_xor(s, 1);  s += __shfl_xor(s, 2);  s += __shfl_xor(s, 4);
  s += __shfl_xor(s, 8);  s += __shfl_xor(s, 16); s += __shfl_xor(s, 32);
  __shared__ float part[2];
  if ((t & 63) == 0) part[t >> 6] = s;
  __syncthreads();
  if (t == 0) out[b] = part[0] + part[1];
}

extern "C" void kernel_launch(void* const* d_in, const int* in_sizes, int n_in,
                              void* d_out, int out_size, void* d_ws, size_t ws_size,
                              hipStream_t stream) {
  const float* qemb  = (const float*)d_in[0];
  const float* demb  = (const float*)d_in[1];
  const float* qmask = (const float*)d_in[2];
  const float* dmask = (const float*)d_in[3];
  const float* w1 = (const float*)d_in[4];
  const float* b1 = (const float*)d_in[5];
  const float* w2 = (const float*)d_in[6];
  const float* b2 = (const float*)d_in[7];
  const float* w3 = (const float*)d_in[8];
  const float* b3 = (const float*)d_in[9];
  const float* dw = (const float*)d_in[10];

  unsigned short* wt = (unsigned short*)d_ws;        // 245760 bf16
  unsigned short* qn = wt + 245760;                  // 1474560 bf16
  unsigned short* dn = qn + 1474560;                 // 12582912 bf16
  float*          pkq4 = (float*)(dn + 12582912);    // 1520640 f32

  prep_w<<<960, 256, 0, stream>>>(w1, w2, w3, wt);
  conv2<2><<<dim3(1, 128), 256, 0, stream>>>(qemb, 30, wt, b1, b2, b3, qn);
  conv2<4><<<dim3(4, 128), 256, 0, stream>>>(demb, 256, wt, b1, b2, b3, dn);
  pool_mfma<<<dim3(12, 128), 64, 0, stream>>>(qn, dn, qmask, dmask, pkq4);
  final_kernel<<<128, 128, 0, stream>>>(pkq4, qmask, dw, (float*)d_out);
}

// Round 5
// 194.303 us; speedup vs baseline: 1.2067x; 1.2067x over previous
//
#include <hip/hip_runtime.h>
#include <math.h>

// Conv-KNRM on MI355X. B=128, QLEN=30, DLEN=256, EMB=300 (pad 320), C=128.
//
// Pipeline:
//   prep_w   : w fp32 [C,E,k] -> wt2 bf16 fragment-order
//              [plane(6)][cb(8)][ec(10)][lane(64)][8] -- one wave B-frag = 1KB dense
//   conv_all : merged doc(512 blocks, MI=4) + query(128 blocks, MI=2) fused
//              3-gram conv. A staged once to LDS; B frags from global with
//              explicit 2-deep ec software pipeline; NO K-loop barriers.
//              bias+relu+L2norm -> bf16 [g][b][l][c]
//   pool_mfma: LDS-free MFMA cos, RBF x11, d-sum -> pkq4 partials
//   final    : sum chunks, log/clip/qmask/sum_q dot dense_w -> out[128]
//
// ws: wt2 bf16 245760 | qn bf16 1474560 | dn bf16 12582912 | pkq4 f32 1520640

typedef __bf16 bf16x8 __attribute__((ext_vector_type(8)));
typedef float f32x4 __attribute__((ext_vector_type(4)));

#if __has_builtin(__builtin_amdgcn_exp2f)
#define EXP2F(x) __builtin_amdgcn_exp2f(x)
#else
#define EXP2F(x) exp2f(x)
#endif

static __device__ __forceinline__ unsigned short f2bf(float f) {
  union { float f; unsigned int u; } v; v.f = f;
  unsigned int r = v.u + 0x7FFFu + ((v.u >> 16) & 1u);  // RNE
  return (unsigned short)(r >> 16);
}

// wt2 linear index: (((p*8 + cb)*10 + ec)*64 + lane)*8 + jj
//   c = cb*16 + (lane&15); e = ec*32 + (lane>>4)*8 + jj
__global__ __launch_bounds__(256) void prep_w(
    const float* __restrict__ w1, const float* __restrict__ w2,
    const float* __restrict__ w3, unsigned short* __restrict__ wt2) {
  int idx = blockIdx.x * 256 + threadIdx.x;
  if (idx >= 245760) return;
  int jj   = idx & 7;
  int lane = (idx >> 3) & 63;
  int ec   = (idx >> 9) % 10;
  int cb   = (idx / 5120) & 7;
  int p    = idx / 40960;
  const float* w; int k, jt;
  if (p == 0)      { w = w1; k = 1; jt = 0; }
  else if (p <= 2) { w = w2; k = 2; jt = p - 1; }
  else             { w = w3; k = 3; jt = p - 3; }
  int c = cb * 16 + (lane & 15);
  int e = ec * 32 + (lane >> 4) * 8 + jj;
  float v = (e < 300) ? w[(c * 300 + e) * k + jt] : 0.0f;
  wt2[idx] = f2bf(v);
}

// B-frag register index for (ni, j): order of the 12 loads per ec.
__device__ __forceinline__ constexpr int bIndex(int ni, int j) {
  constexpr int base[6] = {0, 1, 2, 4, 6, 9};
  return base[ni] + j;
}

template<int MI>
__device__ __forceinline__ void conv_body(
    unsigned short* As, float (*ssq)[64],
    const float* __restrict__ x, int L, int l0, int b,
    const unsigned short* __restrict__ wt2,
    const float* __restrict__ b1, const float* __restrict__ b2,
    const float* __restrict__ b3,
    unsigned short* __restrict__ out) {
  constexpr int ROWS = MI * 16 + 2;
  const int t = threadIdx.x;
  const int w = __builtin_amdgcn_readfirstlane(t >> 6);
  const int lane = t & 63;
  const int quad = lane >> 4, lrow = lane & 15;

  if (t < 192) ssq[t >> 6][t & 63] = 0.0f;

  // stage A once: fp32 -> bf16, rows l0..l0+ROWS-1, e 0..319 (zero pad)
  const float* xb = x + (size_t)b * L * 300;
  for (int idx = t; idx < ROWS * 80; idx += 256) {
    int r = idx / 80, e4 = idx % 80;
    int e = e4 * 4;
    int l = l0 + r;
    float4 v = make_float4(0.f, 0.f, 0.f, 0.f);
    if (l < L && e < 300) v = *reinterpret_cast<const float4*>(xb + l * 300 + e);
    unsigned int lo = (unsigned int)f2bf(v.x) | ((unsigned int)f2bf(v.y) << 16);
    unsigned int hi = (unsigned int)f2bf(v.z) | ((unsigned int)f2bf(v.w) << 16);
    *reinterpret_cast<uint2*>(&As[r * 328 + e]) = make_uint2(lo, hi);
  }
  __syncthreads();

  const float* biases[3] = {b1, b2, b3};
  float bv[6];
  #pragma unroll
  for (int ni = 0; ni < 6; ++ni)
    bv[ni] = biases[ni >> 1][((ni & 1) * 4 + w) * 16 + lrow];

  f32x4 acc[MI][6];
  #pragma unroll
  for (int mi = 0; mi < MI; ++mi)
    #pragma unroll
    for (int ni = 0; ni < 6; ++ni) acc[mi][ni] = (f32x4){0.f, 0.f, 0.f, 0.f};

  const unsigned short* wl = wt2 + lane * 8;

  // load the 12 B-frags for one ec chunk (dense 1KB per wave per load)
  auto loadB = [&](int ec, bf16x8* dst) {
    #pragma unroll
    for (int ni = 0; ni < 6; ++ni) {
      const int g = ni >> 1;
      const int cb = (ni & 1) * 4 + w;
      const int pst = (g * (g + 1)) >> 1;
      #pragma unroll
      for (int j = 0; j <= g; ++j)
        dst[bIndex(ni, j)] = *reinterpret_cast<const bf16x8*>(
            wl + ((((pst + j) * 8 + cb) * 10 + ec) << 9));
    }
  };

  auto compute = [&](int ec, const bf16x8* B) {
    #pragma unroll
    for (int j = 0; j < 3; ++j) {
      bf16x8 af[MI];
      #pragma unroll
      for (int mi = 0; mi < MI; ++mi)
        af[mi] = *reinterpret_cast<const bf16x8*>(
            &As[(mi * 16 + lrow + j) * 328 + ec * 32 + quad * 8]);
      #pragma unroll
      for (int ni = 0; ni < 6; ++ni) {
        const int g = ni >> 1;
        if (j <= g) {
          #pragma unroll
          for (int mi = 0; mi < MI; ++mi)
            acc[mi][ni] = __builtin_amdgcn_mfma_f32_16x16x32_bf16(
                af[mi], B[bIndex(ni, j)], acc[mi][ni], 0, 0, 0);
        }
      }
    }
  };

  // explicit 2-deep software pipeline over the 10 ec chunks, no barriers
  bf16x8 Bc[12], Bn[12];
  loadB(0, Bc);
  #pragma unroll
  for (int e2 = 0; e2 < 5; ++e2) {
    loadB(2 * e2 + 1, Bn);
    compute(2 * e2, Bc);
    if (e2 < 4) loadB(2 * e2 + 2, Bc);
    compute(2 * e2 + 1, Bn);
  }

  // epilogue: ssq per (gram, row) across waves, then normalize + store
  #pragma unroll
  for (int mi = 0; mi < MI; ++mi) {
    #pragma unroll
    for (int r = 0; r < 4; ++r) {
      #pragma unroll
      for (int g = 0; g < 3; ++g) {
        float y0 = fmaxf(acc[mi][2 * g + 0][r] + bv[2 * g + 0], 0.f);
        float y1 = fmaxf(acc[mi][2 * g + 1][r] + bv[2 * g + 1], 0.f);
        float p = y0 * y0 + y1 * y1;
        p += __shfl_xor(p, 1); p += __shfl_xor(p, 2);
        p += __shfl_xor(p, 4); p += __shfl_xor(p, 8);
        if (lrow == 0) atomicAdd(&ssq[g][mi * 16 + quad * 4 + r], p);
      }
    }
  }
  __syncthreads();

  #pragma unroll
  for (int mi = 0; mi < MI; ++mi) {
    #pragma unroll
    for (int r = 0; r < 4; ++r) {
      int row = mi * 16 + quad * 4 + r;
      int l = l0 + row;
      if (l < L) {
        #pragma unroll
        for (int g = 0; g < 3; ++g) {
          float inv = 1.0f / (sqrtf(ssq[g][row]) + 1e-13f);
          #pragma unroll
          for (int h = 0; h < 2; ++h) {
            int ni = 2 * g + h;
            int ch = ((ni & 1) * 4 + w) * 16 + lrow;
            float y = fmaxf(acc[mi][ni][r] + bv[ni], 0.f);
            out[((size_t)(g * 128 + b) * L + l) * 128 + ch] = f2bf(y * inv);
          }
        }
      }
    }
  }
}

// blocks 0..511: doc (MI=4, l0 = (bi&3)*64, b = bi>>2)
// blocks 512..639: query (MI=2, b = bi-512)
__global__ __launch_bounds__(256) void conv_all(
    const float* __restrict__ qemb, const float* __restrict__ demb,
    const unsigned short* __restrict__ wt2,
    const float* __restrict__ b1, const float* __restrict__ b2,
    const float* __restrict__ b3,
    unsigned short* __restrict__ qn, unsigned short* __restrict__ dn) {
  __shared__ unsigned short As[66 * 328];
  __shared__ float ssq[3][64];
  const int bi = blockIdx.x;
  if (bi < 512)
    conv_body<4>(As, ssq, demb, 256, (bi & 3) * 64, bi >> 2, wt2, b1, b2, b3, dn);
  else
    conv_body<2>(As, ssq, qemb, 30, 0, bi - 512, wt2, b1, b2, b3, qn);
}

// One wave per (tg, b, dchunk of 64). A = doc rows (M=d), B = query rows
// (N=q), K = c = 128. RBF features accumulate per-lane; quad shfl reduce.
__global__ __launch_bounds__(64) void pool_mfma(
    const unsigned short* __restrict__ qn, const unsigned short* __restrict__ dn,
    const float* __restrict__ qmask, const float* __restrict__ dmask,
    float* __restrict__ pkq4) {
  const float MU[11] = {1.0f, 0.9f, 0.7f, 0.5f, 0.3f, 0.1f,
                        -0.1f, -0.3f, -0.5f, -0.7f, -0.9f};
  const float NEGC[11] = {-721347.52f, -72.134752f, -72.134752f, -72.134752f,
                          -72.134752f, -72.134752f, -72.134752f, -72.134752f,
                          -72.134752f, -72.134752f, -72.134752f};
  const int tg    = blockIdx.x >> 2;
  const int chunk = blockIdx.x & 3;
  const int b     = blockIdx.y;
  const int lane  = threadIdx.x;
  const int quad  = lane >> 4, l15 = lane & 15;
  const int d0    = chunk * 64;

  const unsigned short* dslab = dn + (size_t)(tg * 128 + b) * 256 * 128;

  bf16x8 aD[4][4];
  #pragma unroll
  for (int mi = 0; mi < 4; ++mi)
    #pragma unroll
    for (int kt = 0; kt < 4; ++kt)
      aD[mi][kt] = *reinterpret_cast<const bf16x8*>(
          dslab + (size_t)(d0 + mi * 16 + l15) * 128 + kt * 32 + quad * 8);

  float dmv[4][4];
  #pragma unroll
  for (int mi = 0; mi < 4; ++mi)
    #pragma unroll
    for (int r = 0; r < 4; ++r)
      dmv[mi][r] = dmask[b * 256 + d0 + mi * 16 + quad * 4 + r];

  float qmv[2];
  qmv[0] = qmask[b * 30 + l15];
  qmv[1] = (16 + l15 < 30) ? qmask[b * 30 + 16 + l15] : 0.0f;

  #pragma unroll 1
  for (int ig = 0; ig < 3; ++ig) {
    const unsigned short* qslab = qn + (size_t)(ig * 128 + b) * 30 * 128;

    bf16x8 bQ[2][4];
    #pragma unroll
    for (int ni = 0; ni < 2; ++ni)
      #pragma unroll
      for (int kt = 0; kt < 4; ++kt)
        bQ[ni][kt] = *reinterpret_cast<const bf16x8*>(
            qslab + (size_t)(ni * 16 + l15) * 128 + kt * 32 + quad * 8);

    f32x4 acc[4][2];
    #pragma unroll
    for (int mi = 0; mi < 4; ++mi)
      #pragma unroll
      for (int ni = 0; ni < 2; ++ni) acc[mi][ni] = (f32x4){0.f, 0.f, 0.f, 0.f};

    #pragma unroll
    for (int kt = 0; kt < 4; ++kt)
      #pragma unroll
      for (int mi = 0; mi < 4; ++mi)
        #pragma unroll
        for (int ni = 0; ni < 2; ++ni)
          acc[mi][ni] = __builtin_amdgcn_mfma_f32_16x16x32_bf16(
              aD[mi][kt], bQ[ni][kt], acc[mi][ni], 0, 0, 0);

    float feat[2][11];
    #pragma unroll
    for (int ni = 0; ni < 2; ++ni)
      #pragma unroll
      for (int kk = 0; kk < 11; ++kk) feat[ni][kk] = 0.0f;

    #pragma unroll
    for (int mi = 0; mi < 4; ++mi) {
      #pragma unroll
      for (int r = 0; r < 4; ++r) {
        #pragma unroll
        for (int ni = 0; ni < 2; ++ni) {
          float m  = qmv[ni] * dmv[mi][r];
          float cm = acc[mi][ni][r] * m;
          #pragma unroll
          for (int kk = 0; kk < 11; ++kk) {
            float d2 = cm - MU[kk];
            feat[ni][kk] += EXP2F(d2 * d2 * NEGC[kk]) * m;
          }
        }
      }
    }

    #pragma unroll
    for (int ni = 0; ni < 2; ++ni)
      #pragma unroll
      for (int kk = 0; kk < 11; ++kk) {
        float v = feat[ni][kk];
        v += __shfl_xor(v, 16);
        v += __shfl_xor(v, 32);
        feat[ni][kk] = v;
      }

    if (quad == 0) {
      const int pair = ig * 3 + tg;
      #pragma unroll
      for (int ni = 0; ni < 2; ++ni) {
        int q = ni * 16 + l15;
        if (q < 30) {
          float* p = pkq4 +
              (((size_t)(chunk * 9 + pair) * 128 + b) * 30 + q) * 11;
          #pragma unroll
          for (int kk = 0; kk < 11; ++kk) p[kk] = feat[ni][kk];
        }
      }
    }
  }
}

__global__ __launch_bounds__(128) void final_kernel(
    const float* __restrict__ pkq4, const float* __restrict__ qmask,
    const float* __restrict__ dw, float* __restrict__ out) {
  const int CH = 9 * 128 * 30 * 11;  // 380160
  const int b = blockIdx.x;
  const int t = threadIdx.x;
  float s = 0.0f;
  for (int idx = t; idx < 9 * 30 * 11; idx += 128) {
    int pair = idx / 330;
    int rem  = idx % 330;
    int q    = rem / 11;
    int kk   = rem % 11;
    size_t base = (((size_t)pair * 128 + b) * 30 + q) * 11 + kk;
    float v = pkq4[base] + pkq4[base + CH] + pkq4[base + 2 * CH] +
              pkq4[base + 3 * CH];
    s += __logf(fmaxf(v, 1e-10f)) * 0.01f * qmask[b * 30 + q] * dw[pair * 11 + kk];
  }
  s += __shfl_xor(s, 1);  s += __shfl_xor(s, 2);  s += __shfl_xor(s, 4);
  s += __shfl_xor(s, 8);  s += __shfl_xor(s, 16); s += __shfl_xor(s, 32);
  __shared__ float part[2];
  if ((t & 63) == 0) part[t >> 6] = s;
  __syncthreads();
  if (t == 0) out[b] = part[0] + part[1];
}

extern "C" void kernel_launch(void* const* d_in, const int* in_sizes, int n_in,
                              void* d_out, int out_size, void* d_ws, size_t ws_size,
                              hipStream_t stream) {
  const float* qemb  = (const float*)d_in[0];
  const float* demb  = (const float*)d_in[1];
  const float* qmask = (const float*)d_in[2];
  const float* dmask = (const float*)d_in[3];
  const float* w1 = (const float*)d_in[4];
  const float* b1 = (const float*)d_in[5];
  const float* w2 = (const float*)d_in[6];
  const float* b2 = (const float*)d_in[7];
  const float* w3 = (const float*)d_in[8];
  const float* b3 = (const float*)d_in[9];
  const float* dw = (const float*)d_in[10];

  unsigned short* wt2 = (unsigned short*)d_ws;       // 245760 bf16
  unsigned short* qn = wt2 + 245760;                 // 1474560 bf16
  unsigned short* dn = qn + 1474560;                 // 12582912 bf16
  float*          pkq4 = (float*)(dn + 12582912);    // 1520640 f32

  prep_w<<<960, 256, 0, stream>>>(w1, w2, w3, wt2);
  conv_all<<<640, 256, 0, stream>>>(qemb, demb, wt2, b1, b2, b3, qn, dn);
  pool_mfma<<<dim3(12, 128), 64, 0, stream>>>(qn, dn, qmask, dmask, pkq4);
  final_kernel<<<128, 128, 0, stream>>>(pkq4, qmask, dw, (float*)d_out);
}